// Round 5
// baseline (233.224 us; speedup 1.0000x reference)
//
#include <hip/hip_runtime.h>
#include <hip/hip_cooperative_groups.h>
#include <math.h>

namespace cg = cooperative_groups;

#define D_FEAT 64
typedef _Float16 v8h __attribute__((ext_vector_type(8)));
typedef float v4f __attribute__((ext_vector_type(4)));
typedef _Float16 h2 __attribute__((ext_vector_type(2)));

__device__ __forceinline__ v8h u2h8(uint4 u) { v8h v; __builtin_memcpy(&v, &u, 16); return v; }
__device__ __forceinline__ unsigned pkh(float a, float b) {
    h2 r = {(_Float16)a, (_Float16)b};
    unsigned u; __builtin_memcpy(&u, &r, 4); return u;
}

#define XCP_PITCH 144
#define WAVE_LDS  (32 * XCP_PITCH)   /* 4608 B per wave */

// ============================================================================
// Mega-kernel: phase A (prep, grid-stride) -> grid.sync -> phase B (fused,
// grid-stride over 16-node tiles, 2 cooperating waves per 128-thr block).
// Rationale: fused phase is pinned at ~2.6 TB/s L2-fill (saturated gather
// path, occupancy-insensitive r0-r4) => attack the ~20-25us of launch gaps
// by collapsing 2 kernels + inter-kernel idle into one cooperative dispatch.
// ============================================================================
__global__ __launch_bounds__(128)
void agnn_mega(const float* __restrict__ x, const float* __restrict__ beta_p,
               const int* __restrict__ edge_row, const int* __restrict__ edge_col,
               float* __restrict__ rn, int* __restrict__ row_ptr,
               uint2* __restrict__ xh, float* __restrict__ out,
               int n_nodes, int n_edges) {
    __shared__ char lds_raw[2 * WAVE_LDS];
    const uint4* xh4 = (const uint4*)xh;
    int gsize = gridDim.x * blockDim.x;
    int gtid  = blockIdx.x * blockDim.x + threadIdx.x;

    // ---- Phase A1: per-node rsqrt-norm + f16 feature table (16 thr/node) ----
    int nwork = n_nodes * 16;
    for (int t = gtid; t < nwork; t += gsize) {
        int node = t >> 4;
        int l4   = t & 15;
        float4 v = ((const float4*)x)[t];
        float ss = v.x*v.x + v.y*v.y + v.z*v.z + v.w*v.w;
        #pragma unroll
        for (int off = 1; off < 16; off <<= 1) ss += __shfl_xor(ss, off, 64);
        if (l4 == 0) rn[node] = ss > 0.f ? rsqrtf(ss) : 0.f;
        h2 h0 = {(_Float16)v.x, (_Float16)v.y};
        h2 h1 = {(_Float16)v.z, (_Float16)v.w};
        uint2 u;
        __builtin_memcpy(&u.x, &h0, 4);
        __builtin_memcpy(&u.y, &h1, 4);
        xh[t] = u;
    }
    // ---- Phase A2: CSR row offsets via boundary scatter (rows sorted) ----
    for (int e = gtid; e < n_edges; e += gsize) {
        int r1 = edge_row[e];
        int r0 = (e == 0) ? -1 : edge_row[e - 1];
        for (int r = r0 + 1; r <= r1; ++r) row_ptr[r] = e;
        if (e == n_edges - 1)
            for (int r = r1 + 1; r <= n_nodes; ++r) row_ptr[r] = n_edges;
    }

    cg::this_grid().sync();

    // ---- Phase B: block-sparse flash-style fused, grid-stride over tiles ----
    int wid  = threadIdx.x >> 6;
    int lane = threadIdx.x & 63;
    int q    = lane >> 4;
    int lo4  = lane & 15;
    char* XCP = lds_raw + wid * WAVE_LDS;

    float beta  = beta_p[0];
    float shift = fabsf(beta);
    unsigned int selp = (lo4 & 1) ? 0x07060302u : 0x05040100u;
    int srcA = ((q & 1) << 5) + lo4;
    int srcB = srcA + 16;
    int tiles = (n_nodes + 15) >> 4;

    for (int tile = blockIdx.x; tile < tiles; tile += gridDim.x) {
        int t0 = tile * 16;

        int qnode = t0 + lo4; if (qnode >= n_nodes) qnode = n_nodes - 1;
        v8h a0 = u2h8(xh4[(size_t)qnode * 8 + q]);
        v8h a1 = u2h8(xh4[(size_t)qnode * 8 + 4 + q]);

        int rb = t0 + q * 4;
        float brn = beta * rn[qnode];
        int es   = row_ptr[t0];
        int tend = t0 + 16; if (tend > n_nodes) tend = n_nodes;
        int L    = row_ptr[tend] - es;
        int blo  = row_ptr[min(t0 + lo4,     n_nodes)] - es;
        int bhi  = row_ptr[min(t0 + lo4 + 1, n_nodes)] - es;

        v4f o0 = {0,0,0,0}, o1 = {0,0,0,0}, o2 = {0,0,0,0}, o3 = {0,0,0,0};
        float lsum = 0.f;

        int nch  = (L + 31) >> 5;
        int nchw = (nch > wid) ? ((nch - wid + 1) >> 1) : 0;
        if (nchw > 0) {
            int cc0, cc1;
            {
                int i0 = (wid << 5) + lo4, i1 = i0 + 16;
                cc0 = edge_col[es + (i0 < L ? i0 : 0)];
                cc1 = edge_col[es + (i1 < L ? i1 : 0)];
            }
            float rc0 = rn[cc0], rc1 = rn[cc1];
            uint4 A00 = xh4[(size_t)cc0 * 8 + q];
            uint4 A01 = xh4[(size_t)cc0 * 8 + 4 + q];
            uint4 A10 = xh4[(size_t)cc1 * 8 + q];
            uint4 A11 = xh4[(size_t)cc1 * 8 + 4 + q];

            for (int k = 0; k < nchw; ++k) {
                int base = (wid + 2 * k) << 5;
                bool more = (k + 1) < nchw;

                int nc0, nc1;
                if (more) {
                    int i0 = base + 64 + lo4, i1 = i0 + 16;
                    nc0 = edge_col[es + (i0 < L ? i0 : 0)];
                    nc1 = edge_col[es + (i1 < L ? i1 : 0)];
                } else { nc0 = cc0; nc1 = cc1; }

                v4f z0 = {0,0,0,0};
                z0 = __builtin_amdgcn_mfma_f32_16x16x32_f16(u2h8(A00), a0, z0, 0, 0, 0);
                z0 = __builtin_amdgcn_mfma_f32_16x16x32_f16(u2h8(A01), a1, z0, 0, 0, 0);
                v4f z1 = {0,0,0,0};
                z1 = __builtin_amdgcn_mfma_f32_16x16x32_f16(u2h8(A10), a0, z1, 0, 0, 0);
                z1 = __builtin_amdgcn_mfma_f32_16x16x32_f16(u2h8(A11), a1, z1, 0, 0, 0);

                {
                    unsigned int colA = lo4 * 4, colB = (16 + lo4) * 4;
                    char* pA = XCP + (4 * q) * XCP_PITCH;
                    char* pB = XCP + (16 + 4 * q) * XCP_PITCH;
                    *(unsigned int*)(pA + 0 * XCP_PITCH + colA) = A00.x;
                    *(unsigned int*)(pA + 1 * XCP_PITCH + colA) = A00.y;
                    *(unsigned int*)(pA + 2 * XCP_PITCH + colA) = A00.z;
                    *(unsigned int*)(pA + 3 * XCP_PITCH + colA) = A00.w;
                    *(unsigned int*)(pB + 0 * XCP_PITCH + colA) = A01.x;
                    *(unsigned int*)(pB + 1 * XCP_PITCH + colA) = A01.y;
                    *(unsigned int*)(pB + 2 * XCP_PITCH + colA) = A01.z;
                    *(unsigned int*)(pB + 3 * XCP_PITCH + colA) = A01.w;
                    *(unsigned int*)(pA + 0 * XCP_PITCH + colB) = A10.x;
                    *(unsigned int*)(pA + 1 * XCP_PITCH + colB) = A10.y;
                    *(unsigned int*)(pA + 2 * XCP_PITCH + colB) = A10.z;
                    *(unsigned int*)(pA + 3 * XCP_PITCH + colB) = A10.w;
                    *(unsigned int*)(pB + 0 * XCP_PITCH + colB) = A11.x;
                    *(unsigned int*)(pB + 1 * XCP_PITCH + colB) = A11.y;
                    *(unsigned int*)(pB + 2 * XCP_PITCH + colB) = A11.z;
                    *(unsigned int*)(pB + 3 * XCP_PITCH + colB) = A11.w;
                }

                float nr0, nr1; uint4 B00, B01, B10, B11;
                if (more) {
                    nr0 = rn[nc0]; nr1 = rn[nc1];
                    B00 = xh4[(size_t)nc0 * 8 + q];
                    B01 = xh4[(size_t)nc0 * 8 + 4 + q];
                    B10 = xh4[(size_t)nc1 * 8 + q];
                    B11 = xh4[(size_t)nc1 * 8 + 4 + q];
                } else {
                    nr0 = rc0; nr1 = rc1;
                    B00 = A00; B01 = A01; B10 = A10; B11 = A11;
                }

                float rA0 = __shfl(rc0, 4*q + 0), rA1 = __shfl(rc0, 4*q + 1);
                float rA2 = __shfl(rc0, 4*q + 2), rA3 = __shfl(rc0, 4*q + 3);
                float rB0 = __shfl(rc1, 4*q + 0), rB1 = __shfl(rc1, 4*q + 1);
                float rB2 = __shfl(rc1, 4*q + 2), rB3 = __shfl(rc1, 4*q + 3);

                int eA = base + 4 * q, eB = eA + 16;
                float wA0 = (eA+0 >= blo && eA+0 < bhi) ? __expf(brn * rA0 * z0[0] - shift) : 0.f;
                float wA1 = (eA+1 >= blo && eA+1 < bhi) ? __expf(brn * rA1 * z0[1] - shift) : 0.f;
                float wA2 = (eA+2 >= blo && eA+2 < bhi) ? __expf(brn * rA2 * z0[2] - shift) : 0.f;
                float wA3 = (eA+3 >= blo && eA+3 < bhi) ? __expf(brn * rA3 * z0[3] - shift) : 0.f;
                float wB0 = (eB+0 >= blo && eB+0 < bhi) ? __expf(brn * rB0 * z1[0] - shift) : 0.f;
                float wB1 = (eB+1 >= blo && eB+1 < bhi) ? __expf(brn * rB1 * z1[1] - shift) : 0.f;
                float wB2 = (eB+2 >= blo && eB+2 < bhi) ? __expf(brn * rB2 * z1[2] - shift) : 0.f;
                float wB3 = (eB+3 >= blo && eB+3 < bhi) ? __expf(brn * rB3 * z1[3] - shift) : 0.f;
                lsum += ((wA0 + wA1) + (wA2 + wA3)) + ((wB0 + wB1) + (wB2 + wB3));

                unsigned d0 = pkh(wA0, wA1), d1 = pkh(wA2, wA3);
                unsigned e0 = pkh(wB0, wB1), e1 = pkh(wB2, wB3);
                unsigned uA0 = __shfl((int)d0, srcA), uA1 = __shfl((int)d1, srcA);
                unsigned uB0 = __shfl((int)d0, srcB), uB1 = __shfl((int)d1, srcB);
                unsigned vA0 = __shfl((int)e0, srcA), vA1 = __shfl((int)e1, srcA);
                unsigned vB0 = __shfl((int)e0, srcB), vB1 = __shfl((int)e1, srcB);
                uint4 pu;
                if (q < 2) { pu.x = uA0; pu.y = uA1; pu.z = uB0; pu.w = uB1; }
                else       { pu.x = vA0; pu.y = vA1; pu.z = vB0; pu.w = vB1; }
                v8h pah = u2h8(pu);

                {
                    const char* rp = XCP + (0 + (lo4 >> 1)) * XCP_PITCH + q * 32;
                    uint4 da = *(const uint4*)rp;
                    uint4 db = *(const uint4*)(rp + 16);
                    uint4 bb = { __builtin_amdgcn_perm(da.y, da.x, selp),
                                 __builtin_amdgcn_perm(da.w, da.z, selp),
                                 __builtin_amdgcn_perm(db.y, db.x, selp),
                                 __builtin_amdgcn_perm(db.w, db.z, selp) };
                    o0 = __builtin_amdgcn_mfma_f32_16x16x32_f16(pah, u2h8(bb), o0, 0, 0, 0);
                }
                {
                    const char* rp = XCP + (8 + (lo4 >> 1)) * XCP_PITCH + q * 32;
                    uint4 da = *(const uint4*)rp;
                    uint4 db = *(const uint4*)(rp + 16);
                    uint4 bb = { __builtin_amdgcn_perm(da.y, da.x, selp),
                                 __builtin_amdgcn_perm(da.w, da.z, selp),
                                 __builtin_amdgcn_perm(db.y, db.x, selp),
                                 __builtin_amdgcn_perm(db.w, db.z, selp) };
                    o1 = __builtin_amdgcn_mfma_f32_16x16x32_f16(pah, u2h8(bb), o1, 0, 0, 0);
                }
                {
                    const char* rp = XCP + (16 + (lo4 >> 1)) * XCP_PITCH + q * 32;
                    uint4 da = *(const uint4*)rp;
                    uint4 db = *(const uint4*)(rp + 16);
                    uint4 bb = { __builtin_amdgcn_perm(da.y, da.x, selp),
                                 __builtin_amdgcn_perm(da.w, da.z, selp),
                                 __builtin_amdgcn_perm(db.y, db.x, selp),
                                 __builtin_amdgcn_perm(db.w, db.z, selp) };
                    o2 = __builtin_amdgcn_mfma_f32_16x16x32_f16(pah, u2h8(bb), o2, 0, 0, 0);
                }
                {
                    const char* rp = XCP + (24 + (lo4 >> 1)) * XCP_PITCH + q * 32;
                    uint4 da = *(const uint4*)rp;
                    uint4 db = *(const uint4*)(rp + 16);
                    uint4 bb = { __builtin_amdgcn_perm(da.y, da.x, selp),
                                 __builtin_amdgcn_perm(da.w, da.z, selp),
                                 __builtin_amdgcn_perm(db.y, db.x, selp),
                                 __builtin_amdgcn_perm(db.w, db.z, selp) };
                    o3 = __builtin_amdgcn_mfma_f32_16x16x32_f16(pah, u2h8(bb), o3, 0, 0, 0);
                }

                cc0 = nc0; cc1 = nc1; rc0 = nr0; rc1 = nr1;
                A00 = B00; A01 = B01; A10 = B10; A11 = B11;
            }
        }

        // ---- cross-wave combine (wave1 scratch = its own XCP region) ----
        if (wid == 1) {
            char* ST = XCP;
            *(v4f*)(ST + lane * 68 +  0) = o0;
            *(v4f*)(ST + lane * 68 + 16) = o1;
            *(v4f*)(ST + lane * 68 + 32) = o2;
            *(v4f*)(ST + lane * 68 + 48) = o3;
            *(float*)(ST + 64 * 68 + lane * 4) = lsum;
        }
        __syncthreads();
        if (wid == 0) {
            const char* ST = lds_raw + WAVE_LDS;
            o0 += *(const v4f*)(ST + lane * 68 +  0);
            o1 += *(const v4f*)(ST + lane * 68 + 16);
            o2 += *(const v4f*)(ST + lane * 68 + 32);
            o3 += *(const v4f*)(ST + lane * 68 + 48);
            lsum += *(const float*)(ST + 64 * 68 + lane * 4);

            lsum += __shfl_xor(lsum, 16, 64);
            lsum += __shfl_xor(lsum, 32, 64);
            float inv = lsum > 0.f ? 1.f / lsum : 0.f;
            float i0 = __shfl(inv, 4*q + 0);
            float i1 = __shfl(inv, 4*q + 1);
            float i2 = __shfl(inv, 4*q + 2);
            float i3 = __shfl(inv, 4*q + 3);

            int m0 = rb;
            if (m0 + 0 < n_nodes) { float* p = out + (size_t)(m0 + 0) * 64 + lo4;
                p[0] = o0[0]*i0; p[16] = o1[0]*i0; p[32] = o2[0]*i0; p[48] = o3[0]*i0; }
            if (m0 + 1 < n_nodes) { float* p = out + (size_t)(m0 + 1) * 64 + lo4;
                p[0] = o0[1]*i1; p[16] = o1[1]*i1; p[32] = o2[1]*i1; p[48] = o3[1]*i1; }
            if (m0 + 2 < n_nodes) { float* p = out + (size_t)(m0 + 2) * 64 + lo4;
                p[0] = o0[2]*i2; p[16] = o1[2]*i2; p[32] = o2[2]*i2; p[48] = o3[2]*i2; }
            if (m0 + 3 < n_nodes) { float* p = out + (size_t)(m0 + 3) * 64 + lo4;
                p[0] = o0[3]*i3; p[16] = o1[3]*i3; p[32] = o2[3]*i3; p[48] = o3[3]*i3; }
        }
        __syncthreads();   // wave0 must finish reading scratch before wave1's next staging
    }
}

// ============================================================================
// Fallback path (r4 two-kernel structure) if cooperative launch unavailable.
// ============================================================================
__global__ __launch_bounds__(256)
void agnn_prep(const float* __restrict__ x, float* __restrict__ rn,
               uint2* __restrict__ xh, const int* __restrict__ edge_row,
               int* __restrict__ row_ptr, int n_nodes, int n_edges, int nb_prep) {
    if ((int)blockIdx.x < nb_prep) {
        int t = blockIdx.x * blockDim.x + threadIdx.x;
        int node = t >> 4;
        if (node >= n_nodes) return;
        int l4 = t & 15;
        float4 v = ((const float4*)x)[node * 16 + l4];
        float ss = v.x*v.x + v.y*v.y + v.z*v.z + v.w*v.w;
        #pragma unroll
        for (int off = 1; off < 16; off <<= 1) ss += __shfl_xor(ss, off, 64);
        if (l4 == 0) rn[node] = ss > 0.f ? rsqrtf(ss) : 0.f;
        h2 h0 = {(_Float16)v.x, (_Float16)v.y};
        h2 h1 = {(_Float16)v.z, (_Float16)v.w};
        uint2 u;
        __builtin_memcpy(&u.x, &h0, 4);
        __builtin_memcpy(&u.y, &h1, 4);
        xh[node * 16 + l4] = u;
    } else {
        int e = (blockIdx.x - nb_prep) * blockDim.x + threadIdx.x;
        if (e >= n_edges) return;
        int r1 = edge_row[e];
        int r0 = (e == 0) ? -1 : edge_row[e - 1];
        for (int r = r0 + 1; r <= r1; ++r) row_ptr[r] = e;
        if (e == n_edges - 1)
            for (int r = r1 + 1; r <= n_nodes; ++r) row_ptr[r] = n_edges;
    }
}

__global__ __launch_bounds__(128)
void agnn_fused(const float* __restrict__ beta_p,
                const int* __restrict__ edge_col,
                const int* __restrict__ row_ptr,
                const float* __restrict__ rn,
                const uint4* __restrict__ xh4,
                float* __restrict__ out, int n_nodes) {
    __shared__ char lds_raw[2 * WAVE_LDS];
    int wid  = threadIdx.x >> 6;
    int lane = threadIdx.x & 63;
    int q    = lane >> 4;
    int lo4  = lane & 15;
    char* XCP = lds_raw + wid * WAVE_LDS;

    int tile = blockIdx.x;
    int t0 = tile * 16;
    if (t0 >= n_nodes) return;

    int qnode = t0 + lo4; if (qnode >= n_nodes) qnode = n_nodes - 1;
    v8h a0 = u2h8(xh4[(size_t)qnode * 8 + q]);
    v8h a1 = u2h8(xh4[(size_t)qnode * 8 + 4 + q]);

    float beta  = beta_p[0];
    float shift = fabsf(beta);
    float brn = beta * rn[qnode];
    int es   = row_ptr[t0];
    int tend = t0 + 16; if (tend > n_nodes) tend = n_nodes;
    int L    = row_ptr[tend] - es;
    int blo  = row_ptr[min(t0 + lo4,     n_nodes)] - es;
    int bhi  = row_ptr[min(t0 + lo4 + 1, n_nodes)] - es;

    v4f o0 = {0,0,0,0}, o1 = {0,0,0,0}, o2 = {0,0,0,0}, o3 = {0,0,0,0};
    float lsum = 0.f;
    unsigned int selp = (lo4 & 1) ? 0x07060302u : 0x05040100u;
    int srcA = ((q & 1) << 5) + lo4;
    int srcB = srcA + 16;

    int nch  = (L + 31) >> 5;
    int nchw = (nch > wid) ? ((nch - wid + 1) >> 1) : 0;
    if (nchw > 0) {
        int cc0, cc1;
        {
            int i0 = (wid << 5) + lo4, i1 = i0 + 16;
            cc0 = edge_col[es + (i0 < L ? i0 : 0)];
            cc1 = edge_col[es + (i1 < L ? i1 : 0)];
        }
        float rc0 = rn[cc0], rc1 = rn[cc1];
        uint4 A00 = xh4[(size_t)cc0 * 8 + q];
        uint4 A01 = xh4[(size_t)cc0 * 8 + 4 + q];
        uint4 A10 = xh4[(size_t)cc1 * 8 + q];
        uint4 A11 = xh4[(size_t)cc1 * 8 + 4 + q];

        for (int k = 0; k < nchw; ++k) {
            int base = (wid + 2 * k) << 5;
            bool more = (k + 1) < nchw;

            int nc0, nc1;
            if (more) {
                int i0 = base + 64 + lo4, i1 = i0 + 16;
                nc0 = edge_col[es + (i0 < L ? i0 : 0)];
                nc1 = edge_col[es + (i1 < L ? i1 : 0)];
            } else { nc0 = cc0; nc1 = cc1; }

            v4f z0 = {0,0,0,0};
            z0 = __builtin_amdgcn_mfma_f32_16x16x32_f16(u2h8(A00), a0, z0, 0, 0, 0);
            z0 = __builtin_amdgcn_mfma_f32_16x16x32_f16(u2h8(A01), a1, z0, 0, 0, 0);
            v4f z1 = {0,0,0,0};
            z1 = __builtin_amdgcn_mfma_f32_16x16x32_f16(u2h8(A10), a0, z1, 0, 0, 0);
            z1 = __builtin_amdgcn_mfma_f32_16x16x32_f16(u2h8(A11), a1, z1, 0, 0, 0);

            {
                unsigned int colA = lo4 * 4, colB = (16 + lo4) * 4;
                char* pA = XCP + (4 * q) * XCP_PITCH;
                char* pB = XCP + (16 + 4 * q) * XCP_PITCH;
                *(unsigned int*)(pA + 0 * XCP_PITCH + colA) = A00.x;
                *(unsigned int*)(pA + 1 * XCP_PITCH + colA) = A00.y;
                *(unsigned int*)(pA + 2 * XCP_PITCH + colA) = A00.z;
                *(unsigned int*)(pA + 3 * XCP_PITCH + colA) = A00.w;
                *(unsigned int*)(pB + 0 * XCP_PITCH + colA) = A01.x;
                *(unsigned int*)(pB + 1 * XCP_PITCH + colA) = A01.y;
                *(unsigned int*)(pB + 2 * XCP_PITCH + colA) = A01.z;
                *(unsigned int*)(pB + 3 * XCP_PITCH + colA) = A01.w;
                *(unsigned int*)(pA + 0 * XCP_PITCH + colB) = A10.x;
                *(unsigned int*)(pA + 1 * XCP_PITCH + colB) = A10.y;
                *(unsigned int*)(pA + 2 * XCP_PITCH + colB) = A10.z;
                *(unsigned int*)(pA + 3 * XCP_PITCH + colB) = A10.w;
                *(unsigned int*)(pB + 0 * XCP_PITCH + colB) = A11.x;
                *(unsigned int*)(pB + 1 * XCP_PITCH + colB) = A11.y;
                *(unsigned int*)(pB + 2 * XCP_PITCH + colB) = A11.z;
                *(unsigned int*)(pB + 3 * XCP_PITCH + colB) = A11.w;
            }

            float nr0, nr1; uint4 B00, B01, B10, B11;
            if (more) {
                nr0 = rn[nc0]; nr1 = rn[nc1];
                B00 = xh4[(size_t)nc0 * 8 + q];
                B01 = xh4[(size_t)nc0 * 8 + 4 + q];
                B10 = xh4[(size_t)nc1 * 8 + q];
                B11 = xh4[(size_t)nc1 * 8 + 4 + q];
            } else {
                nr0 = rc0; nr1 = rc1;
                B00 = A00; B01 = A01; B10 = A10; B11 = A11;
            }

            float rA0 = __shfl(rc0, 4*q + 0), rA1 = __shfl(rc0, 4*q + 1);
            float rA2 = __shfl(rc0, 4*q + 2), rA3 = __shfl(rc0, 4*q + 3);
            float rB0 = __shfl(rc1, 4*q + 0), rB1 = __shfl(rc1, 4*q + 1);
            float rB2 = __shfl(rc1, 4*q + 2), rB3 = __shfl(rc1, 4*q + 3);

            int eA = base + 4 * q, eB = eA + 16;
            float wA0 = (eA+0 >= blo && eA+0 < bhi) ? __expf(brn * rA0 * z0[0] - shift) : 0.f;
            float wA1 = (eA+1 >= blo && eA+1 < bhi) ? __expf(brn * rA1 * z0[1] - shift) : 0.f;
            float wA2 = (eA+2 >= blo && eA+2 < bhi) ? __expf(brn * rA2 * z0[2] - shift) : 0.f;
            float wA3 = (eA+3 >= blo && eA+3 < bhi) ? __expf(brn * rA3 * z0[3] - shift) : 0.f;
            float wB0 = (eB+0 >= blo && eB+0 < bhi) ? __expf(brn * rB0 * z1[0] - shift) : 0.f;
            float wB1 = (eB+1 >= blo && eB+1 < bhi) ? __expf(brn * rB1 * z1[1] - shift) : 0.f;
            float wB2 = (eB+2 >= blo && eB+2 < bhi) ? __expf(brn * rB2 * z1[2] - shift) : 0.f;
            float wB3 = (eB+3 >= blo && eB+3 < bhi) ? __expf(brn * rB3 * z1[3] - shift) : 0.f;
            lsum += ((wA0 + wA1) + (wA2 + wA3)) + ((wB0 + wB1) + (wB2 + wB3));

            unsigned d0 = pkh(wA0, wA1), d1 = pkh(wA2, wA3);
            unsigned e0 = pkh(wB0, wB1), e1 = pkh(wB2, wB3);
            unsigned uA0 = __shfl((int)d0, srcA), uA1 = __shfl((int)d1, srcA);
            unsigned uB0 = __shfl((int)d0, srcB), uB1 = __shfl((int)d1, srcB);
            unsigned vA0 = __shfl((int)e0, srcA), vA1 = __shfl((int)e1, srcA);
            unsigned vB0 = __shfl((int)e0, srcB), vB1 = __shfl((int)e1, srcB);
            uint4 pu;
            if (q < 2) { pu.x = uA0; pu.y = uA1; pu.z = uB0; pu.w = uB1; }
            else       { pu.x = vA0; pu.y = vA1; pu.z = vB0; pu.w = vB1; }
            v8h pah = u2h8(pu);

            {
                const char* rp = XCP + (0 + (lo4 >> 1)) * XCP_PITCH + q * 32;
                uint4 da = *(const uint4*)rp;
                uint4 db = *(const uint4*)(rp + 16);
                uint4 bb = { __builtin_amdgcn_perm(da.y, da.x, selp),
                             __builtin_amdgcn_perm(da.w, da.z, selp),
                             __builtin_amdgcn_perm(db.y, db.x, selp),
                             __builtin_amdgcn_perm(db.w, db.z, selp) };
                o0 = __builtin_amdgcn_mfma_f32_16x16x32_f16(pah, u2h8(bb), o0, 0, 0, 0);
            }
            {
                const char* rp = XCP + (8 + (lo4 >> 1)) * XCP_PITCH + q * 32;
                uint4 da = *(const uint4*)rp;
                uint4 db = *(const uint4*)(rp + 16);
                uint4 bb = { __builtin_amdgcn_perm(da.y, da.x, selp),
                             __builtin_amdgcn_perm(da.w, da.z, selp),
                             __builtin_amdgcn_perm(db.y, db.x, selp),
                             __builtin_amdgcn_perm(db.w, db.z, selp) };
                o1 = __builtin_amdgcn_mfma_f32_16x16x32_f16(pah, u2h8(bb), o1, 0, 0, 0);
            }
            {
                const char* rp = XCP + (16 + (lo4 >> 1)) * XCP_PITCH + q * 32;
                uint4 da = *(const uint4*)rp;
                uint4 db = *(const uint4*)(rp + 16);
                uint4 bb = { __builtin_amdgcn_perm(da.y, da.x, selp),
                             __builtin_amdgcn_perm(da.w, da.z, selp),
                             __builtin_amdgcn_perm(db.y, db.x, selp),
                             __builtin_amdgcn_perm(db.w, db.z, selp) };
                o2 = __builtin_amdgcn_mfma_f32_16x16x32_f16(pah, u2h8(bb), o2, 0, 0, 0);
            }
            {
                const char* rp = XCP + (24 + (lo4 >> 1)) * XCP_PITCH + q * 32;
                uint4 da = *(const uint4*)rp;
                uint4 db = *(const uint4*)(rp + 16);
                uint4 bb = { __builtin_amdgcn_perm(da.y, da.x, selp),
                             __builtin_amdgcn_perm(da.w, da.z, selp),
                             __builtin_amdgcn_perm(db.y, db.x, selp),
                             __builtin_amdgcn_perm(db.w, db.z, selp) };
                o3 = __builtin_amdgcn_mfma_f32_16x16x32_f16(pah, u2h8(bb), o3, 0, 0, 0);
            }

            cc0 = nc0; cc1 = nc1; rc0 = nr0; rc1 = nr1;
            A00 = B00; A01 = B01; A10 = B10; A11 = B11;
        }
    }

    if (wid == 1) {
        char* ST = XCP;
        *(v4f*)(ST + lane * 68 +  0) = o0;
        *(v4f*)(ST + lane * 68 + 16) = o1;
        *(v4f*)(ST + lane * 68 + 32) = o2;
        *(v4f*)(ST + lane * 68 + 48) = o3;
        *(float*)(ST + 64 * 68 + lane * 4) = lsum;
    }
    __syncthreads();
    if (wid == 1) return;
    {
        const char* ST = lds_raw + WAVE_LDS;
        o0 += *(const v4f*)(ST + lane * 68 +  0);
        o1 += *(const v4f*)(ST + lane * 68 + 16);
        o2 += *(const v4f*)(ST + lane * 68 + 32);
        o3 += *(const v4f*)(ST + lane * 68 + 48);
        lsum += *(const float*)(ST + 64 * 68 + lane * 4);
    }

    lsum += __shfl_xor(lsum, 16, 64);
    lsum += __shfl_xor(lsum, 32, 64);
    float inv = lsum > 0.f ? 1.f / lsum : 0.f;
    float i0 = __shfl(inv, 4*q + 0);
    float i1 = __shfl(inv, 4*q + 1);
    float i2 = __shfl(inv, 4*q + 2);
    float i3 = __shfl(inv, 4*q + 3);

    int m0 = t0 + q * 4;
    if (m0 + 0 < n_nodes) { float* p = out + (size_t)(m0 + 0) * 64 + lo4;
        p[0] = o0[0]*i0; p[16] = o1[0]*i0; p[32] = o2[0]*i0; p[48] = o3[0]*i0; }
    if (m0 + 1 < n_nodes) { float* p = out + (size_t)(m0 + 1) * 64 + lo4;
        p[0] = o0[1]*i1; p[16] = o1[1]*i1; p[32] = o2[1]*i1; p[48] = o3[1]*i1; }
    if (m0 + 2 < n_nodes) { float* p = out + (size_t)(m0 + 2) * 64 + lo4;
        p[0] = o0[2]*i2; p[16] = o1[2]*i2; p[32] = o2[2]*i2; p[48] = o3[2]*i2; }
    if (m0 + 3 < n_nodes) { float* p = out + (size_t)(m0 + 3) * 64 + lo4;
        p[0] = o0[3]*i3; p[16] = o1[3]*i3; p[32] = o2[3]*i3; p[48] = o3[3]*i3; }
}

extern "C" void kernel_launch(void* const* d_in, const int* in_sizes, int n_in,
                              void* d_out, int out_size, void* d_ws, size_t ws_size,
                              hipStream_t stream) {
    const float* x        = (const float*)d_in[0];
    const float* beta     = (const float*)d_in[1];
    const int*   edge_row = (const int*)d_in[2];
    const int*   edge_col = (const int*)d_in[3];
    float* out = (float*)d_out;

    int n_nodes = in_sizes[0] / D_FEAT;
    int n_edges = in_sizes[2];

    char* ws = (char*)d_ws;
    float* rn = (float*)ws;
    size_t off0 = ((size_t)n_nodes * sizeof(float) + 255) & ~(size_t)255;
    int* row_ptr = (int*)(ws + off0);
    size_t off1 = off0 + (((size_t)(n_nodes + 1) * sizeof(int) + 255) & ~(size_t)255);
    uint2* xh = (uint2*)(ws + off1);

    // One-time capability probe (host-side queries only; graph-capture safe).
    static int coop_grid = -1;
    if (coop_grid < 0) {
        int dev = 0; hipGetDevice(&dev);
        int sup = 0;
        hipDeviceGetAttribute(&sup, hipDeviceAttributeCooperativeLaunch, dev);
        int maxb = 0, ncu = 0;
        hipOccupancyMaxActiveBlocksPerMultiprocessor(&maxb, agnn_mega, 128, 0);
        hipDeviceGetAttribute(&ncu, hipDeviceAttributeMultiprocessorCount, dev);
        coop_grid = (sup && maxb > 0 && ncu > 0) ? maxb * ncu : 0;
    }

    int tiles = (n_nodes + 15) / 16;
    if (coop_grid > 0) {
        int grid = coop_grid < tiles ? coop_grid : tiles;
        void* args[] = {(void*)&x, (void*)&beta, (void*)&edge_row, (void*)&edge_col,
                        (void*)&rn, (void*)&row_ptr, (void*)&xh, (void*)&out,
                        (void*)&n_nodes, (void*)&n_edges};
        hipError_t err = hipLaunchCooperativeKernel((void*)agnn_mega, dim3(grid),
                                                    dim3(128), args, 0, stream);
        if (err == hipSuccess) return;
        coop_grid = 0;  // disable and fall through to two-kernel path
    }

    {
        int nb_prep = (n_nodes * 16 + 255) / 256;
        int nb_rp   = (n_edges + 255) / 256;
        agnn_prep<<<nb_prep + nb_rp, 256, 0, stream>>>(
            x, rn, xh, edge_row, row_ptr, n_nodes, n_edges, nb_prep);
        agnn_fused<<<tiles, 128, 0, stream>>>(beta, edge_col, row_ptr,
                                              rn, (const uint4*)xh, out, n_nodes);
    }
}

// Round 6
// 129.111 us; speedup vs baseline: 1.8064x; 1.8064x over previous
//
#include <hip/hip_runtime.h>
#include <math.h>

#define D_FEAT 64
typedef _Float16 v8h __attribute__((ext_vector_type(8)));
typedef float v4f __attribute__((ext_vector_type(4)));
typedef _Float16 h2 __attribute__((ext_vector_type(2)));

__device__ __forceinline__ v8h u2h8(uint4 u) { v8h v; __builtin_memcpy(&v, &u, 16); return v; }
__device__ __forceinline__ unsigned pkh(float a, float b) {
    h2 r = {(_Float16)a, (_Float16)b};
    unsigned u; __builtin_memcpy(&u, &r, 4); return u;
}

// ---- K0 (merged): blocks [0,nb_prep): per-node rsqrt-norm + f16 copy of x.
//      blocks [nb_prep,..): CSR row offsets via boundary scatter (rows sorted).
__global__ __launch_bounds__(256)
void agnn_prep(const float* __restrict__ x, float* __restrict__ rn,
               uint2* __restrict__ xh, const int* __restrict__ edge_row,
               int* __restrict__ row_ptr, int n_nodes, int n_edges, int nb_prep) {
    if ((int)blockIdx.x < nb_prep) {
        int t = blockIdx.x * blockDim.x + threadIdx.x;
        int node = t >> 4;
        if (node >= n_nodes) return;
        int l4 = t & 15;
        float4 v = ((const float4*)x)[node * 16 + l4];
        float ss = v.x*v.x + v.y*v.y + v.z*v.z + v.w*v.w;
        #pragma unroll
        for (int off = 1; off < 16; off <<= 1) ss += __shfl_xor(ss, off, 64);
        if (l4 == 0) rn[node] = ss > 0.f ? rsqrtf(ss) : 0.f;
        h2 h0 = {(_Float16)v.x, (_Float16)v.y};
        h2 h1 = {(_Float16)v.z, (_Float16)v.w};
        uint2 u;
        __builtin_memcpy(&u.x, &h0, 4);
        __builtin_memcpy(&u.y, &h1, 4);
        xh[node * 16 + l4] = u;
    } else {
        int e = (blockIdx.x - nb_prep) * blockDim.x + threadIdx.x;
        if (e >= n_edges) return;
        int r1 = edge_row[e];
        int r0 = (e == 0) ? -1 : edge_row[e - 1];
        for (int r = r0 + 1; r <= r1; ++r) row_ptr[r] = e;
        if (e == n_edges - 1)
            for (int r = r1 + 1; r <= n_nodes; ++r) row_ptr[r] = n_edges;
    }
}

// ---- K1: block-sparse flash-style fused kernel, 2 cooperating waves/tile ----
// One 128-thr block per tile of 16 nodes; wave w owns chunks w, w+2, ...
// Swapped QK^T (z = mfma(Xc, Q)) keeps P row-local; in-register P-dance.
// 2-DEEP PIPELINE: feats for chunks k+1 AND k+2 in flight, cols for k+3 in
// flight (~24 outstanding gather ops/wave).  Final falsifier of the
// latency-vs-saturation question for the 2.6 TB/s gather-fill plateau.
// Layouts per guide Sec.3: C/D col=lane&15,row=quad*4+reg; A m=lane&15,k=quad*8+j.
#define XCP_PITCH 144
#define WAVE_LDS  (32 * XCP_PITCH)   /* 4608 B per wave */

__global__ __launch_bounds__(128)
void agnn_fused(const float* __restrict__ beta_p,
                const int* __restrict__ edge_col,
                const int* __restrict__ row_ptr,
                const float* __restrict__ rn,
                const uint4* __restrict__ xh4,
                float* __restrict__ out, int n_nodes) {
    __shared__ char lds_raw[2 * WAVE_LDS];
    int wid  = threadIdx.x >> 6;
    int lane = threadIdx.x & 63;
    int q    = lane >> 4;
    int lo4  = lane & 15;
    char* XCP = lds_raw + wid * WAVE_LDS;

    int tile = blockIdx.x;
    int t0 = tile * 16;
    if (t0 >= n_nodes) return;

    int qnode = t0 + lo4; if (qnode >= n_nodes) qnode = n_nodes - 1;
    v8h a0 = u2h8(xh4[(size_t)qnode * 8 + q]);
    v8h a1 = u2h8(xh4[(size_t)qnode * 8 + 4 + q]);

    float beta  = beta_p[0];
    float shift = fabsf(beta);
    float brn = beta * rn[qnode];
    int es   = row_ptr[t0];
    int tend = t0 + 16; if (tend > n_nodes) tend = n_nodes;
    int L    = row_ptr[tend] - es;
    int blo  = row_ptr[min(t0 + lo4,     n_nodes)] - es;
    int bhi  = row_ptr[min(t0 + lo4 + 1, n_nodes)] - es;

    v4f o0 = {0,0,0,0}, o1 = {0,0,0,0}, o2 = {0,0,0,0}, o3 = {0,0,0,0};
    float lsum = 0.f;
    unsigned int selp = (lo4 & 1) ? 0x07060302u : 0x05040100u;
    int srcA = ((q & 1) << 5) + lo4;
    int srcB = srcA + 16;

    int nch  = (L + 31) >> 5;
    int nchw = (nch > wid) ? ((nch - wid + 1) >> 1) : 0;
#define LOADC(j, d0, d1) do { \
        int _i0 = ((wid + 2 * (j)) << 5) + lo4, _i1 = _i0 + 16; \
        d0 = edge_col[es + (_i0 < L ? _i0 : 0)]; \
        d1 = edge_col[es + (_i1 < L ? _i1 : 0)]; } while (0)

    if (nchw > 0) {
        // Slot A: chunk 0 (will be consumed first).
        int cc0, cc1;
        LOADC(0, cc0, cc1);
        float rc0 = rn[cc0], rc1 = rn[cc1];
        uint4 A00 = xh4[(size_t)cc0 * 8 + q];
        uint4 A01 = xh4[(size_t)cc0 * 8 + 4 + q];
        uint4 A10 = xh4[(size_t)cc1 * 8 + q];
        uint4 A11 = xh4[(size_t)cc1 * 8 + 4 + q];
        // Slot B: chunk 1 (in flight).
        float rd0 = rc0, rd1 = rc1;
        uint4 B00 = A00, B01 = A01, B10 = A10, B11 = A11;
        if (nchw > 1) {
            int c10, c11; LOADC(1, c10, c11);
            rd0 = rn[c10]; rd1 = rn[c11];
            B00 = xh4[(size_t)c10 * 8 + q];
            B01 = xh4[(size_t)c10 * 8 + 4 + q];
            B10 = xh4[(size_t)c11 * 8 + q];
            B11 = xh4[(size_t)c11 * 8 + 4 + q];
        }
        // Cols for chunk 2 (in flight).
        int cC0 = cc0, cC1 = cc1;
        if (nchw > 2) LOADC(2, cC0, cC1);

        for (int k = 0; k < nchw; ++k) {
            int base = (wid + 2 * k) << 5;

            // QK^T on current chunk (vmcnt wait for A-regs: issued 2 iters ago).
            v4f z0 = {0,0,0,0};
            z0 = __builtin_amdgcn_mfma_f32_16x16x32_f16(u2h8(A00), a0, z0, 0, 0, 0);
            z0 = __builtin_amdgcn_mfma_f32_16x16x32_f16(u2h8(A01), a1, z0, 0, 0, 0);
            v4f z1 = {0,0,0,0};
            z1 = __builtin_amdgcn_mfma_f32_16x16x32_f16(u2h8(A10), a0, z1, 0, 0, 0);
            z1 = __builtin_amdgcn_mfma_f32_16x16x32_f16(u2h8(A11), a1, z1, 0, 0, 0);

            // Stage current chunk's features to XCP for the PV B-operand.
            {
                unsigned int colA = lo4 * 4, colB = (16 + lo4) * 4;
                char* pA = XCP + (4 * q) * XCP_PITCH;
                char* pB = XCP + (16 + 4 * q) * XCP_PITCH;
                *(unsigned int*)(pA + 0 * XCP_PITCH + colA) = A00.x;
                *(unsigned int*)(pA + 1 * XCP_PITCH + colA) = A00.y;
                *(unsigned int*)(pA + 2 * XCP_PITCH + colA) = A00.z;
                *(unsigned int*)(pA + 3 * XCP_PITCH + colA) = A00.w;
                *(unsigned int*)(pB + 0 * XCP_PITCH + colA) = A01.x;
                *(unsigned int*)(pB + 1 * XCP_PITCH + colA) = A01.y;
                *(unsigned int*)(pB + 2 * XCP_PITCH + colA) = A01.z;
                *(unsigned int*)(pB + 3 * XCP_PITCH + colA) = A01.w;
                *(unsigned int*)(pA + 0 * XCP_PITCH + colB) = A10.x;
                *(unsigned int*)(pA + 1 * XCP_PITCH + colB) = A10.y;
                *(unsigned int*)(pA + 2 * XCP_PITCH + colB) = A10.z;
                *(unsigned int*)(pA + 3 * XCP_PITCH + colB) = A10.w;
                *(unsigned int*)(pB + 0 * XCP_PITCH + colB) = A11.x;
                *(unsigned int*)(pB + 1 * XCP_PITCH + colB) = A11.y;
                *(unsigned int*)(pB + 2 * XCP_PITCH + colB) = A11.z;
                *(unsigned int*)(pB + 3 * XCP_PITCH + colB) = A11.w;
            }

            // Issue chunk k+2's feature/rn gathers (cols landed last iter).
            float re0, re1; uint4 C00, C01, C10, C11;
            if (k + 2 < nchw) {
                re0 = rn[cC0]; re1 = rn[cC1];
                C00 = xh4[(size_t)cC0 * 8 + q];
                C01 = xh4[(size_t)cC0 * 8 + 4 + q];
                C10 = xh4[(size_t)cC1 * 8 + q];
                C11 = xh4[(size_t)cC1 * 8 + 4 + q];
            } else {
                re0 = rd0; re1 = rd1;
                C00 = B00; C01 = B01; C10 = B10; C11 = B11;
            }
            // Issue chunk k+3's col loads.
            if (k + 3 < nchw) LOADC(k + 3, cC0, cC1);

            float rA0 = __shfl(rc0, 4*q + 0), rA1 = __shfl(rc0, 4*q + 1);
            float rA2 = __shfl(rc0, 4*q + 2), rA3 = __shfl(rc0, 4*q + 3);
            float rB0 = __shfl(rc1, 4*q + 0), rB1 = __shfl(rc1, 4*q + 1);
            float rB2 = __shfl(rc1, 4*q + 2), rB3 = __shfl(rc1, 4*q + 3);

            int eA = base + 4 * q, eB = eA + 16;
            float wA0 = (eA+0 >= blo && eA+0 < bhi) ? __expf(brn * rA0 * z0[0] - shift) : 0.f;
            float wA1 = (eA+1 >= blo && eA+1 < bhi) ? __expf(brn * rA1 * z0[1] - shift) : 0.f;
            float wA2 = (eA+2 >= blo && eA+2 < bhi) ? __expf(brn * rA2 * z0[2] - shift) : 0.f;
            float wA3 = (eA+3 >= blo && eA+3 < bhi) ? __expf(brn * rA3 * z0[3] - shift) : 0.f;
            float wB0 = (eB+0 >= blo && eB+0 < bhi) ? __expf(brn * rB0 * z1[0] - shift) : 0.f;
            float wB1 = (eB+1 >= blo && eB+1 < bhi) ? __expf(brn * rB1 * z1[1] - shift) : 0.f;
            float wB2 = (eB+2 >= blo && eB+2 < bhi) ? __expf(brn * rB2 * z1[2] - shift) : 0.f;
            float wB3 = (eB+3 >= blo && eB+3 < bhi) ? __expf(brn * rB3 * z1[3] - shift) : 0.f;
            lsum += ((wA0 + wA1) + (wA2 + wA3)) + ((wB0 + wB1) + (wB2 + wB3));

            // In-register P-dance: A-fragment P[row lo4][edges 8q..8q+7].
            unsigned d0 = pkh(wA0, wA1), d1 = pkh(wA2, wA3);
            unsigned e0 = pkh(wB0, wB1), e1 = pkh(wB2, wB3);
            unsigned uA0 = __shfl((int)d0, srcA), uA1 = __shfl((int)d1, srcA);
            unsigned uB0 = __shfl((int)d0, srcB), uB1 = __shfl((int)d1, srcB);
            unsigned vA0 = __shfl((int)e0, srcA), vA1 = __shfl((int)e1, srcA);
            unsigned vB0 = __shfl((int)e0, srcB), vB1 = __shfl((int)e1, srcB);
            uint4 pu;
            if (q < 2) { pu.x = uA0; pu.y = uA1; pu.z = uB0; pu.w = uB1; }
            else       { pu.x = vA0; pu.y = vA1; pu.z = vB0; pu.w = vB1; }
            v8h pah = u2h8(pu);

            {
                const char* rp = XCP + (0 + (lo4 >> 1)) * XCP_PITCH + q * 32;
                uint4 da = *(const uint4*)rp;
                uint4 db = *(const uint4*)(rp + 16);
                uint4 bb = { __builtin_amdgcn_perm(da.y, da.x, selp),
                             __builtin_amdgcn_perm(da.w, da.z, selp),
                             __builtin_amdgcn_perm(db.y, db.x, selp),
                             __builtin_amdgcn_perm(db.w, db.z, selp) };
                o0 = __builtin_amdgcn_mfma_f32_16x16x32_f16(pah, u2h8(bb), o0, 0, 0, 0);
            }
            {
                const char* rp = XCP + (8 + (lo4 >> 1)) * XCP_PITCH + q * 32;
                uint4 da = *(const uint4*)rp;
                uint4 db = *(const uint4*)(rp + 16);
                uint4 bb = { __builtin_amdgcn_perm(da.y, da.x, selp),
                             __builtin_amdgcn_perm(da.w, da.z, selp),
                             __builtin_amdgcn_perm(db.y, db.x, selp),
                             __builtin_amdgcn_perm(db.w, db.z, selp) };
                o1 = __builtin_amdgcn_mfma_f32_16x16x32_f16(pah, u2h8(bb), o1, 0, 0, 0);
            }
            {
                const char* rp = XCP + (16 + (lo4 >> 1)) * XCP_PITCH + q * 32;
                uint4 da = *(const uint4*)rp;
                uint4 db = *(const uint4*)(rp + 16);
                uint4 bb = { __builtin_amdgcn_perm(da.y, da.x, selp),
                             __builtin_amdgcn_perm(da.w, da.z, selp),
                             __builtin_amdgcn_perm(db.y, db.x, selp),
                             __builtin_amdgcn_perm(db.w, db.z, selp) };
                o2 = __builtin_amdgcn_mfma_f32_16x16x32_f16(pah, u2h8(bb), o2, 0, 0, 0);
            }
            {
                const char* rp = XCP + (24 + (lo4 >> 1)) * XCP_PITCH + q * 32;
                uint4 da = *(const uint4*)rp;
                uint4 db = *(const uint4*)(rp + 16);
                uint4 bb = { __builtin_amdgcn_perm(da.y, da.x, selp),
                             __builtin_amdgcn_perm(da.w, da.z, selp),
                             __builtin_amdgcn_perm(db.y, db.x, selp),
                             __builtin_amdgcn_perm(db.w, db.z, selp) };
                o3 = __builtin_amdgcn_mfma_f32_16x16x32_f16(pah, u2h8(bb), o3, 0, 0, 0);
            }

            // Rotate pipeline state A<-B<-C.
            rc0 = rd0; rc1 = rd1;
            A00 = B00; A01 = B01; A10 = B10; A11 = B11;
            rd0 = re0; rd1 = re1;
            B00 = C00; B01 = C01; B10 = C10; B11 = C11;
        }
    }
#undef LOADC

    // ---- cross-wave combine: wave1 dumps partials into its own XCP region ----
    if (wid == 1) {
        char* ST = XCP;
        *(v4f*)(ST + lane * 68 +  0) = o0;
        *(v4f*)(ST + lane * 68 + 16) = o1;
        *(v4f*)(ST + lane * 68 + 32) = o2;
        *(v4f*)(ST + lane * 68 + 48) = o3;
        *(float*)(ST + 64 * 68 + lane * 4) = lsum;
    }
    __syncthreads();
    if (wid == 1) return;
    {
        const char* ST = lds_raw + WAVE_LDS;
        o0 += *(const v4f*)(ST + lane * 68 +  0);
        o1 += *(const v4f*)(ST + lane * 68 + 16);
        o2 += *(const v4f*)(ST + lane * 68 + 32);
        o3 += *(const v4f*)(ST + lane * 68 + 48);
        lsum += *(const float*)(ST + 64 * 68 + lane * 4);
    }

    lsum += __shfl_xor(lsum, 16, 64);
    lsum += __shfl_xor(lsum, 32, 64);
    float inv = lsum > 0.f ? 1.f / lsum : 0.f;
    float i0 = __shfl(inv, 4*q + 0);
    float i1 = __shfl(inv, 4*q + 1);
    float i2 = __shfl(inv, 4*q + 2);
    float i3 = __shfl(inv, 4*q + 3);

    int m0 = t0 + q * 4;
    if (m0 + 0 < n_nodes) { float* p = out + (size_t)(m0 + 0) * 64 + lo4;
        p[0] = o0[0]*i0; p[16] = o1[0]*i0; p[32] = o2[0]*i0; p[48] = o3[0]*i0; }
    if (m0 + 1 < n_nodes) { float* p = out + (size_t)(m0 + 1) * 64 + lo4;
        p[0] = o0[1]*i1; p[16] = o1[1]*i1; p[32] = o2[1]*i1; p[48] = o3[1]*i1; }
    if (m0 + 2 < n_nodes) { float* p = out + (size_t)(m0 + 2) * 64 + lo4;
        p[0] = o0[2]*i2; p[16] = o1[2]*i2; p[32] = o2[2]*i2; p[48] = o3[2]*i2; }
    if (m0 + 3 < n_nodes) { float* p = out + (size_t)(m0 + 3) * 64 + lo4;
        p[0] = o0[3]*i3; p[16] = o1[3]*i3; p[32] = o2[3]*i3; p[48] = o3[3]*i3; }
}

extern "C" void kernel_launch(void* const* d_in, const int* in_sizes, int n_in,
                              void* d_out, int out_size, void* d_ws, size_t ws_size,
                              hipStream_t stream) {
    const float* x        = (const float*)d_in[0];
    const float* beta     = (const float*)d_in[1];
    const int*   edge_row = (const int*)d_in[2];
    const int*   edge_col = (const int*)d_in[3];
    float* out = (float*)d_out;

    int n_nodes = in_sizes[0] / D_FEAT;
    int n_edges = in_sizes[2];

    char* ws = (char*)d_ws;
    float* rn = (float*)ws;
    size_t off0 = ((size_t)n_nodes * sizeof(float) + 255) & ~(size_t)255;
    int* row_ptr = (int*)(ws + off0);
    size_t off1 = off0 + (((size_t)(n_nodes + 1) * sizeof(int) + 255) & ~(size_t)255);
    uint2* xh = (uint2*)(ws + off1);

    {
        int nb_prep = (n_nodes * 16 + 255) / 256;
        int nb_rp   = (n_edges + 255) / 256;
        agnn_prep<<<nb_prep + nb_rp, 256, 0, stream>>>(
            x, rn, xh, edge_row, row_ptr, n_nodes, n_edges, nb_prep);
    }
    {
        int tiles = (n_nodes + 15) / 16;
        agnn_fused<<<tiles, 128, 0, stream>>>(beta, edge_col, row_ptr,
                                              rn, (const uint4*)xh, out, n_nodes);
    }
}

// Round 8
// 125.166 us; speedup vs baseline: 1.8633x; 1.0315x over previous
//
#include <hip/hip_runtime.h>
#include <math.h>

#define D_FEAT 64
typedef _Float16 v8h __attribute__((ext_vector_type(8)));
typedef float v4f __attribute__((ext_vector_type(4)));
typedef _Float16 h2 __attribute__((ext_vector_type(2)));

__device__ __forceinline__ v8h u2h8(uint4 u) { v8h v; __builtin_memcpy(&v, &u, 16); return v; }
__device__ __forceinline__ unsigned pkh(float a, float b) {
    h2 r = {(_Float16)a, (_Float16)b};
    unsigned u; __builtin_memcpy(&u, &r, 4); return u;
}
// 8 biased-u8 bytes -> 8 f16 holding EXACT ints U-128 in [-127,127].
// {U0,0,U1,0} + 0x65006500 = f16 bits of (1280+U); minus 1408 -> U-128.
// perm codes 0-3 = bytes of 2nd arg, 4-7 = 1st arg (=0) — same convention
// the proven selp perms in this kernel rely on.
__device__ __forceinline__ uint4 dq8(uint2 d) {
    unsigned t0 = __builtin_amdgcn_perm(0u, d.x, 0x04010400u) + 0x65006500u;
    unsigned t1 = __builtin_amdgcn_perm(0u, d.x, 0x04030402u) + 0x65006500u;
    unsigned t2 = __builtin_amdgcn_perm(0u, d.y, 0x04010400u) + 0x65006500u;
    unsigned t3 = __builtin_amdgcn_perm(0u, d.y, 0x04030402u) + 0x65006500u;
    uint4 u = {t0, t1, t2, t3};
    v8h h = u2h8(u);
    const _Float16 c = (_Float16)1408.f;
    v8h o = {c, c, c, c, c, c, c, c};
    h = h - o;
    uint4 r; __builtin_memcpy(&r, &h, 16); return r;
}
// packed {f16 rn', f16 s} -> floats
__device__ __forceinline__ float2 uph(unsigned u) {
    h2 h; __builtin_memcpy(&h, &u, 4);
    return make_float2((float)h[0], (float)h[1]);
}

// ---- K0 (merged): blocks [0,nb_prep): per-node amax + norm + u8 row.
//      rnt[node] = packed f16 {rn' = s/||x||, s = amax/127}.
//      blocks [nb_prep,..): CSR row offsets via boundary scatter (rows sorted).
__global__ __launch_bounds__(256)
void agnn_prep(const float* __restrict__ x, unsigned* __restrict__ rnt,
               unsigned* __restrict__ xq, const int* __restrict__ edge_row,
               int* __restrict__ row_ptr, int n_nodes, int n_edges, int nb_prep) {
    if ((int)blockIdx.x < nb_prep) {
        int t = blockIdx.x * blockDim.x + threadIdx.x;
        int node = t >> 4;
        if (node >= n_nodes) return;
        int l4 = t & 15;
        float4 v = ((const float4*)x)[t];
        float ss = v.x*v.x + v.y*v.y + v.z*v.z + v.w*v.w;
        float am = fmaxf(fmaxf(fabsf(v.x), fabsf(v.y)), fmaxf(fabsf(v.z), fabsf(v.w)));
        #pragma unroll
        for (int off = 1; off < 16; off <<= 1) {
            ss += __shfl_xor(ss, off, 64);
            am = fmaxf(am, __shfl_xor(am, off, 64));
        }
        float inv_s = am > 0.f ? 127.f / am : 0.f;
        unsigned b0 = (unsigned)(int)rintf(v.x * inv_s) + 128u;
        unsigned b1 = (unsigned)(int)rintf(v.y * inv_s) + 128u;
        unsigned b2 = (unsigned)(int)rintf(v.z * inv_s) + 128u;
        unsigned b3 = (unsigned)(int)rintf(v.w * inv_s) + 128u;
        xq[t] = b0 | (b1 << 8) | (b2 << 16) | (b3 << 24);
        if (l4 == 0) {
            float s = am * (1.f / 127.f);
            float nrm = sqrtf(ss);
            float rnp = nrm > 0.f ? s / nrm : 0.f;
            rnt[node] = pkh(rnp, s);
        }
    } else {
        int e = (blockIdx.x - nb_prep) * blockDim.x + threadIdx.x;
        if (e >= n_edges) return;
        int r1 = edge_row[e];
        int r0 = (e == 0) ? -1 : edge_row[e - 1];
        for (int r = r0 + 1; r <= r1; ++r) row_ptr[r] = e;
        if (e == n_edges - 1)
            for (int r = r1 + 1; r <= n_nodes; ++r) row_ptr[r] = n_edges;
    }
}

// ---- K1: fused kernel, 2 waves/tile, u8 table (64 B/edge gathers) ----
// FETCH at f16 was exactly per-XCD COMPULSORY (8 x (1-e^-2) x 12.8MB = 88.5
// vs 88.2 measured) at a saturated ~2.45 TB/s fill rate -> only lever is
// table bytes.  u8 per-node scale: X = round(127 x/amax); dequant in-register
// to EXACT f16 ints (dq8), so QK/PV MFMAs + staging + P-dance are unchanged.
// sim = beta rn'_a rn'_b (X.Y) with rn' = s/||x|| (exact cosine of x-hat);
// PV folds s per edge into P (w' = w s) so out = sum p x-hat; lsum unscaled.
// Layouts per guide Sec.3: C/D col=lane&15,row=quad*4+reg; A m=lane&15,k=quad*8+j.
#define XCP_PITCH 144
#define WAVE_LDS  (32 * XCP_PITCH)   /* 4608 B per wave */

__global__ __launch_bounds__(128)
void agnn_fused(const float* __restrict__ beta_p,
                const int* __restrict__ edge_col,
                const int* __restrict__ row_ptr,
                const unsigned* __restrict__ rnt,
                const uint2* __restrict__ x8,
                float* __restrict__ out, int n_nodes) {
    __shared__ char lds_raw[2 * WAVE_LDS];
    int wid  = threadIdx.x >> 6;
    int lane = threadIdx.x & 63;
    int q    = lane >> 4;
    int lo4  = lane & 15;
    char* XCP = lds_raw + wid * WAVE_LDS;

    int tile = blockIdx.x;
    int t0 = tile * 16;
    if (t0 >= n_nodes) return;

    int qnode = t0 + lo4; if (qnode >= n_nodes) qnode = n_nodes - 1;
    uint2 qL = x8[(size_t)qnode * 8 + q];        // feats 8q..8q+7 (u8)
    uint2 qH = x8[(size_t)qnode * 8 + 4 + q];    // feats 32+8q..  (u8)
    v8h a0 = u2h8(dq8(qL));
    v8h a1 = u2h8(dq8(qH));

    float beta  = beta_p[0];
    float shift = fabsf(beta);
    float2 rq = uph(rnt[qnode]);
    float brn = beta * rq.x;
    int es   = row_ptr[t0];
    int tend = t0 + 16; if (tend > n_nodes) tend = n_nodes;
    int L    = row_ptr[tend] - es;
    int blo  = row_ptr[min(t0 + lo4,     n_nodes)] - es;
    int bhi  = row_ptr[min(t0 + lo4 + 1, n_nodes)] - es;

    v4f o0 = {0,0,0,0}, o1 = {0,0,0,0}, o2 = {0,0,0,0}, o3 = {0,0,0,0};
    float lsum = 0.f;
    unsigned int selp = (lo4 & 1) ? 0x07060302u : 0x05040100u;
    int srcA = ((q & 1) << 5) + lo4;
    int srcB = srcA + 16;

    int nch  = (L + 31) >> 5;
    int nchw = (nch > wid) ? ((nch - wid + 1) >> 1) : 0;  // chunks for this wave
    if (nchw > 0) {
        // Prologue: this wave's chunk 0 (global chunk index = wid).
        int cc0, cc1;
        {
            int i0 = (wid << 5) + lo4, i1 = i0 + 16;
            cc0 = edge_col[es + (i0 < L ? i0 : 0)];
            cc1 = edge_col[es + (i1 < L ? i1 : 0)];
        }
        unsigned rcu0 = rnt[cc0], rcu1 = rnt[cc1];
        uint2 L0 = x8[(size_t)cc0 * 8 + q];
        uint2 H0 = x8[(size_t)cc0 * 8 + 4 + q];
        uint2 L1 = x8[(size_t)cc1 * 8 + q];
        uint2 H1 = x8[(size_t)cc1 * 8 + 4 + q];

        for (int k = 0; k < nchw; ++k) {
            int base = (wid + 2 * k) << 5;
            bool more = (k + 1) < nchw;

            // Prefetch this wave's next chunk (+64 edges) column indices.
            int nc0, nc1;
            if (more) {
                int i0 = base + 64 + lo4, i1 = i0 + 16;
                nc0 = edge_col[es + (i0 < L ? i0 : 0)];
                nc1 = edge_col[es + (i1 < L ? i1 : 0)];
            } else { nc0 = cc0; nc1 = cc1; }

            // Dequantize current chunk to exact-int f16 fragments.
            uint4 A00 = dq8(L0), A01 = dq8(H0), A10 = dq8(L1), A11 = dq8(H1);

            // Swapped QK^T: z0[reg] = (X.Q) for edge base+4q+reg, row lo4.
            v4f z0 = {0,0,0,0};
            z0 = __builtin_amdgcn_mfma_f32_16x16x32_f16(u2h8(A00), a0, z0, 0, 0, 0);
            z0 = __builtin_amdgcn_mfma_f32_16x16x32_f16(u2h8(A01), a1, z0, 0, 0, 0);
            v4f z1 = {0,0,0,0};
            z1 = __builtin_amdgcn_mfma_f32_16x16x32_f16(u2h8(A10), a0, z1, 0, 0, 0);
            z1 = __builtin_amdgcn_mfma_f32_16x16x32_f16(u2h8(A11), a1, z1, 0, 0, 0);

            // Stage dequantized features to XCP (feat-pair-major) for PV B.
            {
                unsigned int colA = lo4 * 4, colB = (16 + lo4) * 4;
                char* pA = XCP + (4 * q) * XCP_PITCH;
                char* pB = XCP + (16 + 4 * q) * XCP_PITCH;
                *(unsigned int*)(pA + 0 * XCP_PITCH + colA) = A00.x;
                *(unsigned int*)(pA + 1 * XCP_PITCH + colA) = A00.y;
                *(unsigned int*)(pA + 2 * XCP_PITCH + colA) = A00.z;
                *(unsigned int*)(pA + 3 * XCP_PITCH + colA) = A00.w;
                *(unsigned int*)(pB + 0 * XCP_PITCH + colA) = A01.x;
                *(unsigned int*)(pB + 1 * XCP_PITCH + colA) = A01.y;
                *(unsigned int*)(pB + 2 * XCP_PITCH + colA) = A01.z;
                *(unsigned int*)(pB + 3 * XCP_PITCH + colA) = A01.w;
                *(unsigned int*)(pA + 0 * XCP_PITCH + colB) = A10.x;
                *(unsigned int*)(pA + 1 * XCP_PITCH + colB) = A10.y;
                *(unsigned int*)(pA + 2 * XCP_PITCH + colB) = A10.z;
                *(unsigned int*)(pA + 3 * XCP_PITCH + colB) = A10.w;
                *(unsigned int*)(pB + 0 * XCP_PITCH + colB) = A11.x;
                *(unsigned int*)(pB + 1 * XCP_PITCH + colB) = A11.y;
                *(unsigned int*)(pB + 2 * XCP_PITCH + colB) = A11.z;
                *(unsigned int*)(pB + 3 * XCP_PITCH + colB) = A11.w;
            }

            // Prefetch next chunk's rows + packed norms/scales.
            unsigned nru0, nru1; uint2 NL0, NH0, NL1, NH1;
            if (more) {
                nru0 = rnt[nc0]; nru1 = rnt[nc1];
                NL0 = x8[(size_t)nc0 * 8 + q];
                NH0 = x8[(size_t)nc0 * 8 + 4 + q];
                NL1 = x8[(size_t)nc1 * 8 + q];
                NH1 = x8[(size_t)nc1 * 8 + 4 + q];
            } else {
                nru0 = rcu0; nru1 = rcu1;
                NL0 = L0; NH0 = H0; NL1 = L1; NH1 = H1;
            }

            // Per-edge {rn', s} for this lane's 8 edges (pull by edge index).
            float2 RA0 = uph(__shfl((int)rcu0, 4*q + 0));
            float2 RA1 = uph(__shfl((int)rcu0, 4*q + 1));
            float2 RA2 = uph(__shfl((int)rcu0, 4*q + 2));
            float2 RA3 = uph(__shfl((int)rcu0, 4*q + 3));
            float2 RB0 = uph(__shfl((int)rcu1, 4*q + 0));
            float2 RB1 = uph(__shfl((int)rcu1, 4*q + 1));
            float2 RB2 = uph(__shfl((int)rcu1, 4*q + 2));
            float2 RB3 = uph(__shfl((int)rcu1, 4*q + 3));

            int eA = base + 4 * q, eB = eA + 16;
            float wA0 = (eA+0 >= blo && eA+0 < bhi) ? __expf(brn * RA0.x * z0[0] - shift) : 0.f;
            float wA1 = (eA+1 >= blo && eA+1 < bhi) ? __expf(brn * RA1.x * z0[1] - shift) : 0.f;
            float wA2 = (eA+2 >= blo && eA+2 < bhi) ? __expf(brn * RA2.x * z0[2] - shift) : 0.f;
            float wA3 = (eA+3 >= blo && eA+3 < bhi) ? __expf(brn * RA3.x * z0[3] - shift) : 0.f;
            float wB0 = (eB+0 >= blo && eB+0 < bhi) ? __expf(brn * RB0.x * z1[0] - shift) : 0.f;
            float wB1 = (eB+1 >= blo && eB+1 < bhi) ? __expf(brn * RB1.x * z1[1] - shift) : 0.f;
            float wB2 = (eB+2 >= blo && eB+2 < bhi) ? __expf(brn * RB2.x * z1[2] - shift) : 0.f;
            float wB3 = (eB+3 >= blo && eB+3 < bhi) ? __expf(brn * RB3.x * z1[3] - shift) : 0.f;
            lsum += ((wA0 + wA1) + (wA2 + wA3)) + ((wB0 + wB1) + (wB2 + wB3));

            // P-dance with per-edge scale folded in: p' = w * s.
            unsigned d0 = pkh(wA0 * RA0.y, wA1 * RA1.y);
            unsigned d1 = pkh(wA2 * RA2.y, wA3 * RA3.y);
            unsigned e0 = pkh(wB0 * RB0.y, wB1 * RB1.y);
            unsigned e1 = pkh(wB2 * RB2.y, wB3 * RB3.y);
            unsigned uA0 = __shfl((int)d0, srcA), uA1 = __shfl((int)d1, srcA);
            unsigned uB0 = __shfl((int)d0, srcB), uB1 = __shfl((int)d1, srcB);
            unsigned vA0 = __shfl((int)e0, srcA), vA1 = __shfl((int)e1, srcA);
            unsigned vB0 = __shfl((int)e0, srcB), vB1 = __shfl((int)e1, srcB);
            uint4 pu;
            if (q < 2) { pu.x = uA0; pu.y = uA1; pu.z = uB0; pu.w = uB1; }
            else       { pu.x = vA0; pu.y = vA1; pu.z = vB0; pu.w = vB1; }
            v8h pah = u2h8(pu);

            {
                const char* rp = XCP + (0 + (lo4 >> 1)) * XCP_PITCH + q * 32;
                uint4 da = *(const uint4*)rp;
                uint4 db = *(const uint4*)(rp + 16);
                uint4 bb = { __builtin_amdgcn_perm(da.y, da.x, selp),
                             __builtin_amdgcn_perm(da.w, da.z, selp),
                             __builtin_amdgcn_perm(db.y, db.x, selp),
                             __builtin_amdgcn_perm(db.w, db.z, selp) };
                o0 = __builtin_amdgcn_mfma_f32_16x16x32_f16(pah, u2h8(bb), o0, 0, 0, 0);
            }
            {
                const char* rp = XCP + (8 + (lo4 >> 1)) * XCP_PITCH + q * 32;
                uint4 da = *(const uint4*)rp;
                uint4 db = *(const uint4*)(rp + 16);
                uint4 bb = { __builtin_amdgcn_perm(da.y, da.x, selp),
                             __builtin_amdgcn_perm(da.w, da.z, selp),
                             __builtin_amdgcn_perm(db.y, db.x, selp),
                             __builtin_amdgcn_perm(db.w, db.z, selp) };
                o1 = __builtin_amdgcn_mfma_f32_16x16x32_f16(pah, u2h8(bb), o1, 0, 0, 0);
            }
            {
                const char* rp = XCP + (16 + (lo4 >> 1)) * XCP_PITCH + q * 32;
                uint4 da = *(const uint4*)rp;
                uint4 db = *(const uint4*)(rp + 16);
                uint4 bb = { __builtin_amdgcn_perm(da.y, da.x, selp),
                             __builtin_amdgcn_perm(da.w, da.z, selp),
                             __builtin_amdgcn_perm(db.y, db.x, selp),
                             __builtin_amdgcn_perm(db.w, db.z, selp) };
                o2 = __builtin_amdgcn_mfma_f32_16x16x32_f16(pah, u2h8(bb), o2, 0, 0, 0);
            }
            {
                const char* rp = XCP + (24 + (lo4 >> 1)) * XCP_PITCH + q * 32;
                uint4 da = *(const uint4*)rp;
                uint4 db = *(const uint4*)(rp + 16);
                uint4 bb = { __builtin_amdgcn_perm(da.y, da.x, selp),
                             __builtin_amdgcn_perm(da.w, da.z, selp),
                             __builtin_amdgcn_perm(db.y, db.x, selp),
                             __builtin_amdgcn_perm(db.w, db.z, selp) };
                o3 = __builtin_amdgcn_mfma_f32_16x16x32_f16(pah, u2h8(bb), o3, 0, 0, 0);
            }

            // Rotate pipeline state.
            cc0 = nc0; cc1 = nc1; rcu0 = nru0; rcu1 = nru1;
            L0 = NL0; H0 = NH0; L1 = NL1; H1 = NH1;
        }
    }

    // ---- cross-wave combine: wave1 dumps partials into its own XCP region ----
    if (wid == 1) {
        char* ST = XCP;
        *(v4f*)(ST + lane * 68 +  0) = o0;
        *(v4f*)(ST + lane * 68 + 16) = o1;
        *(v4f*)(ST + lane * 68 + 32) = o2;
        *(v4f*)(ST + lane * 68 + 48) = o3;
        *(float*)(ST + 64 * 68 + lane * 4) = lsum;
    }
    __syncthreads();
    if (wid == 1) return;
    {
        const char* ST = lds_raw + WAVE_LDS;
        o0 += *(const v4f*)(ST + lane * 68 +  0);
        o1 += *(const v4f*)(ST + lane * 68 + 16);
        o2 += *(const v4f*)(ST + lane * 68 + 32);
        o3 += *(const v4f*)(ST + lane * 68 + 48);
        lsum += *(const float*)(ST + 64 * 68 + lane * 4);
    }

    lsum += __shfl_xor(lsum, 16, 64);
    lsum += __shfl_xor(lsum, 32, 64);
    float inv = lsum > 0.f ? 1.f / lsum : 0.f;
    float i0 = __shfl(inv, 4*q + 0);
    float i1 = __shfl(inv, 4*q + 1);
    float i2 = __shfl(inv, 4*q + 2);
    float i3 = __shfl(inv, 4*q + 3);

    int m0 = t0 + q * 4;
    if (m0 + 0 < n_nodes) { float* p = out + (size_t)(m0 + 0) * 64 + lo4;
        p[0] = o0[0]*i0; p[16] = o1[0]*i0; p[32] = o2[0]*i0; p[48] = o3[0]*i0; }
    if (m0 + 1 < n_nodes) { float* p = out + (size_t)(m0 + 1) * 64 + lo4;
        p[0] = o0[1]*i1; p[16] = o1[1]*i1; p[32] = o2[1]*i1; p[48] = o3[1]*i1; }
    if (m0 + 2 < n_nodes) { float* p = out + (size_t)(m0 + 2) * 64 + lo4;
        p[0] = o0[2]*i2; p[16] = o1[2]*i2; p[32] = o2[2]*i2; p[48] = o3[2]*i2; }
    if (m0 + 3 < n_nodes) { float* p = out + (size_t)(m0 + 3) * 64 + lo4;
        p[0] = o0[3]*i3; p[16] = o1[3]*i3; p[32] = o2[3]*i3; p[48] = o3[3]*i3; }
}

extern "C" void kernel_launch(void* const* d_in, const int* in_sizes, int n_in,
                              void* d_out, int out_size, void* d_ws, size_t ws_size,
                              hipStream_t stream) {
    const float* x        = (const float*)d_in[0];
    const float* beta     = (const float*)d_in[1];
    const int*   edge_row = (const int*)d_in[2];
    const int*   edge_col = (const int*)d_in[3];
    float* out = (float*)d_out;

    int n_nodes = in_sizes[0] / D_FEAT;
    int n_edges = in_sizes[2];

    char* ws = (char*)d_ws;
    unsigned* rnt = (unsigned*)ws;                           // packed {rn', s}
    size_t off0 = ((size_t)n_nodes * 4 + 255) & ~(size_t)255;
    int* row_ptr = (int*)(ws + off0);
    size_t off1 = off0 + (((size_t)(n_nodes + 1) * 4 + 255) & ~(size_t)255);
    unsigned* xq = (unsigned*)(ws + off1);                   // u8 table, 64 B/node

    {
        int nb_prep = (n_nodes * 16 + 255) / 256;
        int nb_rp   = (n_edges + 255) / 256;
        agnn_prep<<<nb_prep + nb_rp, 256, 0, stream>>>(
            x, rnt, xq, edge_row, row_ptr, n_nodes, n_edges, nb_prep);
    }
    {
        int tiles = (n_nodes + 15) / 16;
        agnn_fused<<<tiles, 128, 0, stream>>>(beta, edge_col, row_ptr,
                                              rnt, (const uint2*)xq, out, n_nodes);
    }
}

// Round 9
// 123.769 us; speedup vs baseline: 1.8843x; 1.0113x over previous
//
#include <hip/hip_runtime.h>
#include <math.h>

#define D_FEAT 64
typedef _Float16 v8h __attribute__((ext_vector_type(8)));
typedef float v4f __attribute__((ext_vector_type(4)));
typedef _Float16 h2 __attribute__((ext_vector_type(2)));

__device__ __forceinline__ v8h u2h8(uint4 u) { v8h v; __builtin_memcpy(&v, &u, 16); return v; }
__device__ __forceinline__ unsigned pkh(float a, float b) {
    h2 r = {(_Float16)a, (_Float16)b};
    unsigned u; __builtin_memcpy(&u, &r, 4); return u;
}
__device__ __forceinline__ uint2 lo2(uint4 v) { uint2 r; r.x = v.x; r.y = v.y; return r; }
__device__ __forceinline__ uint2 hi2(uint4 v) { uint2 r; r.x = v.z; r.y = v.w; return r; }
// 8 biased-u8 bytes -> 8 f16 holding EXACT ints U-128 in [-127,127].
// {U0,0,U1,0} + 0x65006500 = f16 bits of (1280+U); minus 1408 -> U-128.
__device__ __forceinline__ uint4 dq8(uint2 d) {
    unsigned t0 = __builtin_amdgcn_perm(0u, d.x, 0x04010400u) + 0x65006500u;
    unsigned t1 = __builtin_amdgcn_perm(0u, d.x, 0x04030402u) + 0x65006500u;
    unsigned t2 = __builtin_amdgcn_perm(0u, d.y, 0x04010400u) + 0x65006500u;
    unsigned t3 = __builtin_amdgcn_perm(0u, d.y, 0x04030402u) + 0x65006500u;
    uint4 u = {t0, t1, t2, t3};
    v8h h = u2h8(u);
    const _Float16 c = (_Float16)1408.f;
    v8h o = {c, c, c, c, c, c, c, c};
    h = h - o;
    uint4 r; __builtin_memcpy(&r, &h, 16); return r;
}
// packed {f16 rn', f16 s} -> floats
__device__ __forceinline__ float2 uph(unsigned u) {
    h2 h; __builtin_memcpy(&h, &u, 4);
    return make_float2((float)h[0], (float)h[1]);
}

// ---- K0 (merged): blocks [0,nb_prep): per-node amax + norm + PERMUTED u8 row.
//      Row qword slots: [f0-7][f32-39][f8-15][f40-47][f16-23][f48-55][f24-31][f56-63]
//      so lane q's single uint4 at offset 16q = {feats 8q..8q+7, feats 32+8q..+7}.
//      rnt[node] = packed f16 {rn' = s/||x||, s = amax/127}.
//      blocks [nb_prep,..): CSR row offsets via boundary scatter (rows sorted).
__global__ __launch_bounds__(256)
void agnn_prep(const float* __restrict__ x, unsigned* __restrict__ rnt,
               unsigned* __restrict__ xq, const int* __restrict__ edge_row,
               int* __restrict__ row_ptr, int n_nodes, int n_edges, int nb_prep) {
    if ((int)blockIdx.x < nb_prep) {
        int t = blockIdx.x * blockDim.x + threadIdx.x;
        int node = t >> 4;
        if (node >= n_nodes) return;
        int l4 = t & 15;
        float4 v = ((const float4*)x)[t];
        float ss = v.x*v.x + v.y*v.y + v.z*v.z + v.w*v.w;
        float am = fmaxf(fmaxf(fabsf(v.x), fabsf(v.y)), fmaxf(fabsf(v.z), fabsf(v.w)));
        #pragma unroll
        for (int off = 1; off < 16; off <<= 1) {
            ss += __shfl_xor(ss, off, 64);
            am = fmaxf(am, __shfl_xor(am, off, 64));
        }
        float inv_s = am > 0.f ? 127.f / am : 0.f;
        unsigned b0 = (unsigned)(int)rintf(v.x * inv_s) + 128u;
        unsigned b1 = (unsigned)(int)rintf(v.y * inv_s) + 128u;
        unsigned b2 = (unsigned)(int)rintf(v.z * inv_s) + 128u;
        unsigned b3 = (unsigned)(int)rintf(v.w * inv_s) + 128u;
        // permuted dword index within the 16-dword row:
        //   l4<8  (feats 4l4..4l4+3 in f0-31):  dd = 4*(l4>>1) + (l4&1)
        //   l4>=8 (feats in f32-63):            dd = 4*((l4-8)>>1) + 2 + (l4&1)
        int dd = (l4 < 8) ? (((l4 >> 1) << 2) | (l4 & 1))
                          : ((((l4 - 8) >> 1) << 2) | 2 | (l4 & 1));
        xq[node * 16 + dd] = b0 | (b1 << 8) | (b2 << 16) | (b3 << 24);
        if (l4 == 0) {
            float s = am * (1.f / 127.f);
            float nrm = sqrtf(ss);
            float rnp = nrm > 0.f ? s / nrm : 0.f;
            rnt[node] = pkh(rnp, s);
        }
    } else {
        int e = (blockIdx.x - nb_prep) * blockDim.x + threadIdx.x;
        if (e >= n_edges) return;
        int r1 = edge_row[e];
        int r0 = (e == 0) ? -1 : edge_row[e - 1];
        for (int r = r0 + 1; r <= r1; ++r) row_ptr[r] = e;
        if (e == n_edges - 1)
            for (int r = r1 + 1; r <= n_nodes; ++r) row_ptr[r] = n_edges;
    }
}

// ---- K1: fused kernel, 2 waves/tile, u8 permuted table, uint4 gathers ----
// Evidence across r0-r8: fused time invariant at ~44us while bytes halved and
// occupancy varied 28-41% -> bound by gather REQUEST throughput, not bytes
// (f16->u8 kept insts + CL-requests constant -> time constant).  This round
// halves feature requests: one uint4/lane (permuted row) replaces two uint2,
// feature VMEM insts 4->2 per chunk, CL-requests 64->32.  Zero added VALU.
// Layouts per guide Sec.3: C/D col=lane&15,row=quad*4+reg; A m=lane&15,k=quad*8+j.
#define XCP_PITCH 144
#define WAVE_LDS  (32 * XCP_PITCH)   /* 4608 B per wave */

__global__ __launch_bounds__(128)
void agnn_fused(const float* __restrict__ beta_p,
                const int* __restrict__ edge_col,
                const int* __restrict__ row_ptr,
                const unsigned* __restrict__ rnt,
                const uint4* __restrict__ x16,
                float* __restrict__ out, int n_nodes) {
    __shared__ char lds_raw[2 * WAVE_LDS];
    int wid  = threadIdx.x >> 6;
    int lane = threadIdx.x & 63;
    int q    = lane >> 4;
    int lo4  = lane & 15;
    char* XCP = lds_raw + wid * WAVE_LDS;

    int tile = blockIdx.x;
    int t0 = tile * 16;
    if (t0 >= n_nodes) return;

    int qnode = t0 + lo4; if (qnode >= n_nodes) qnode = n_nodes - 1;
    uint4 qR = x16[(size_t)qnode * 4 + q];       // {feats 8q.., feats 32+8q..}
    v8h a0 = u2h8(dq8(lo2(qR)));
    v8h a1 = u2h8(dq8(hi2(qR)));

    float beta  = beta_p[0];
    float shift = fabsf(beta);
    float2 rq = uph(rnt[qnode]);
    float brn = beta * rq.x;
    int es   = row_ptr[t0];
    int tend = t0 + 16; if (tend > n_nodes) tend = n_nodes;
    int L    = row_ptr[tend] - es;
    int blo  = row_ptr[min(t0 + lo4,     n_nodes)] - es;
    int bhi  = row_ptr[min(t0 + lo4 + 1, n_nodes)] - es;

    v4f o0 = {0,0,0,0}, o1 = {0,0,0,0}, o2 = {0,0,0,0}, o3 = {0,0,0,0};
    float lsum = 0.f;
    unsigned int selp = (lo4 & 1) ? 0x07060302u : 0x05040100u;
    int srcA = ((q & 1) << 5) + lo4;
    int srcB = srcA + 16;

    int nch  = (L + 31) >> 5;
    int nchw = (nch > wid) ? ((nch - wid + 1) >> 1) : 0;  // chunks for this wave
    if (nchw > 0) {
        // Prologue: this wave's chunk 0 (global chunk index = wid).
        int cc0, cc1;
        {
            int i0 = (wid << 5) + lo4, i1 = i0 + 16;
            cc0 = edge_col[es + (i0 < L ? i0 : 0)];
            cc1 = edge_col[es + (i1 < L ? i1 : 0)];
        }
        unsigned rcu0 = rnt[cc0], rcu1 = rnt[cc1];
        uint4 R0 = x16[(size_t)cc0 * 4 + q];
        uint4 R1 = x16[(size_t)cc1 * 4 + q];

        for (int k = 0; k < nchw; ++k) {
            int base = (wid + 2 * k) << 5;
            bool more = (k + 1) < nchw;

            // Prefetch this wave's next chunk (+64 edges) column indices.
            int nc0, nc1;
            if (more) {
                int i0 = base + 64 + lo4, i1 = i0 + 16;
                nc0 = edge_col[es + (i0 < L ? i0 : 0)];
                nc1 = edge_col[es + (i1 < L ? i1 : 0)];
            } else { nc0 = cc0; nc1 = cc1; }

            // Dequantize current chunk to exact-int f16 fragments.
            uint4 A00 = dq8(lo2(R0)), A01 = dq8(hi2(R0));
            uint4 A10 = dq8(lo2(R1)), A11 = dq8(hi2(R1));

            // Swapped QK^T: z0[reg] = (X.Q) for edge base+4q+reg, row lo4.
            v4f z0 = {0,0,0,0};
            z0 = __builtin_amdgcn_mfma_f32_16x16x32_f16(u2h8(A00), a0, z0, 0, 0, 0);
            z0 = __builtin_amdgcn_mfma_f32_16x16x32_f16(u2h8(A01), a1, z0, 0, 0, 0);
            v4f z1 = {0,0,0,0};
            z1 = __builtin_amdgcn_mfma_f32_16x16x32_f16(u2h8(A10), a0, z1, 0, 0, 0);
            z1 = __builtin_amdgcn_mfma_f32_16x16x32_f16(u2h8(A11), a1, z1, 0, 0, 0);

            // Stage dequantized features to XCP (feat-pair-major) for PV B.
            {
                unsigned int colA = lo4 * 4, colB = (16 + lo4) * 4;
                char* pA = XCP + (4 * q) * XCP_PITCH;
                char* pB = XCP + (16 + 4 * q) * XCP_PITCH;
                *(unsigned int*)(pA + 0 * XCP_PITCH + colA) = A00.x;
                *(unsigned int*)(pA + 1 * XCP_PITCH + colA) = A00.y;
                *(unsigned int*)(pA + 2 * XCP_PITCH + colA) = A00.z;
                *(unsigned int*)(pA + 3 * XCP_PITCH + colA) = A00.w;
                *(unsigned int*)(pB + 0 * XCP_PITCH + colA) = A01.x;
                *(unsigned int*)(pB + 1 * XCP_PITCH + colA) = A01.y;
                *(unsigned int*)(pB + 2 * XCP_PITCH + colA) = A01.z;
                *(unsigned int*)(pB + 3 * XCP_PITCH + colA) = A01.w;
                *(unsigned int*)(pA + 0 * XCP_PITCH + colB) = A10.x;
                *(unsigned int*)(pA + 1 * XCP_PITCH + colB) = A10.y;
                *(unsigned int*)(pA + 2 * XCP_PITCH + colB) = A10.z;
                *(unsigned int*)(pA + 3 * XCP_PITCH + colB) = A10.w;
                *(unsigned int*)(pB + 0 * XCP_PITCH + colB) = A11.x;
                *(unsigned int*)(pB + 1 * XCP_PITCH + colB) = A11.y;
                *(unsigned int*)(pB + 2 * XCP_PITCH + colB) = A11.z;
                *(unsigned int*)(pB + 3 * XCP_PITCH + colB) = A11.w;
            }

            // Prefetch next chunk's rows + packed norms/scales.
            unsigned nru0, nru1; uint4 NR0, NR1;
            if (more) {
                nru0 = rnt[nc0]; nru1 = rnt[nc1];
                NR0 = x16[(size_t)nc0 * 4 + q];
                NR1 = x16[(size_t)nc1 * 4 + q];
            } else {
                nru0 = rcu0; nru1 = rcu1;
                NR0 = R0; NR1 = R1;
            }

            // Per-edge {rn', s} for this lane's 8 edges (pull by edge index).
            float2 RA0 = uph(__shfl((int)rcu0, 4*q + 0));
            float2 RA1 = uph(__shfl((int)rcu0, 4*q + 1));
            float2 RA2 = uph(__shfl((int)rcu0, 4*q + 2));
            float2 RA3 = uph(__shfl((int)rcu0, 4*q + 3));
            float2 RB0 = uph(__shfl((int)rcu1, 4*q + 0));
            float2 RB1 = uph(__shfl((int)rcu1, 4*q + 1));
            float2 RB2 = uph(__shfl((int)rcu1, 4*q + 2));
            float2 RB3 = uph(__shfl((int)rcu1, 4*q + 3));

            int eA = base + 4 * q, eB = eA + 16;
            float wA0 = (eA+0 >= blo && eA+0 < bhi) ? __expf(brn * RA0.x * z0[0] - shift) : 0.f;
            float wA1 = (eA+1 >= blo && eA+1 < bhi) ? __expf(brn * RA1.x * z0[1] - shift) : 0.f;
            float wA2 = (eA+2 >= blo && eA+2 < bhi) ? __expf(brn * RA2.x * z0[2] - shift) : 0.f;
            float wA3 = (eA+3 >= blo && eA+3 < bhi) ? __expf(brn * RA3.x * z0[3] - shift) : 0.f;
            float wB0 = (eB+0 >= blo && eB+0 < bhi) ? __expf(brn * RB0.x * z1[0] - shift) : 0.f;
            float wB1 = (eB+1 >= blo && eB+1 < bhi) ? __expf(brn * RB1.x * z1[1] - shift) : 0.f;
            float wB2 = (eB+2 >= blo && eB+2 < bhi) ? __expf(brn * RB2.x * z1[2] - shift) : 0.f;
            float wB3 = (eB+3 >= blo && eB+3 < bhi) ? __expf(brn * RB3.x * z1[3] - shift) : 0.f;
            lsum += ((wA0 + wA1) + (wA2 + wA3)) + ((wB0 + wB1) + (wB2 + wB3));

            // P-dance with per-edge scale folded in: p' = w * s.
            unsigned d0 = pkh(wA0 * RA0.y, wA1 * RA1.y);
            unsigned d1 = pkh(wA2 * RA2.y, wA3 * RA3.y);
            unsigned e0 = pkh(wB0 * RB0.y, wB1 * RB1.y);
            unsigned e1 = pkh(wB2 * RB2.y, wB3 * RB3.y);
            unsigned uA0 = __shfl((int)d0, srcA), uA1 = __shfl((int)d1, srcA);
            unsigned uB0 = __shfl((int)d0, srcB), uB1 = __shfl((int)d1, srcB);
            unsigned vA0 = __shfl((int)e0, srcA), vA1 = __shfl((int)e1, srcA);
            unsigned vB0 = __shfl((int)e0, srcB), vB1 = __shfl((int)e1, srcB);
            uint4 pu;
            if (q < 2) { pu.x = uA0; pu.y = uA1; pu.z = uB0; pu.w = uB1; }
            else       { pu.x = vA0; pu.y = vA1; pu.z = vB0; pu.w = vB1; }
            v8h pah = u2h8(pu);

            {
                const char* rp = XCP + (0 + (lo4 >> 1)) * XCP_PITCH + q * 32;
                uint4 da = *(const uint4*)rp;
                uint4 db = *(const uint4*)(rp + 16);
                uint4 bb = { __builtin_amdgcn_perm(da.y, da.x, selp),
                             __builtin_amdgcn_perm(da.w, da.z, selp),
                             __builtin_amdgcn_perm(db.y, db.x, selp),
                             __builtin_amdgcn_perm(db.w, db.z, selp) };
                o0 = __builtin_amdgcn_mfma_f32_16x16x32_f16(pah, u2h8(bb), o0, 0, 0, 0);
            }
            {
                const char* rp = XCP + (8 + (lo4 >> 1)) * XCP_PITCH + q * 32;
                uint4 da = *(const uint4*)rp;
                uint4 db = *(const uint4*)(rp + 16);
                uint4 bb = { __builtin_amdgcn_perm(da.y, da.x, selp),
                             __builtin_amdgcn_perm(da.w, da.z, selp),
                             __builtin_amdgcn_perm(db.y, db.x, selp),
                             __builtin_amdgcn_perm(db.w, db.z, selp) };
                o1 = __builtin_amdgcn_mfma_f32_16x16x32_f16(pah, u2h8(bb), o1, 0, 0, 0);
            }
            {
                const char* rp = XCP + (16 + (lo4 >> 1)) * XCP_PITCH + q * 32;
                uint4 da = *(const uint4*)rp;
                uint4 db = *(const uint4*)(rp + 16);
                uint4 bb = { __builtin_amdgcn_perm(da.y, da.x, selp),
                             __builtin_amdgcn_perm(da.w, da.z, selp),
                             __builtin_amdgcn_perm(db.y, db.x, selp),
                             __builtin_amdgcn_perm(db.w, db.z, selp) };
                o2 = __builtin_amdgcn_mfma_f32_16x16x32_f16(pah, u2h8(bb), o2, 0, 0, 0);
            }
            {
                const char* rp = XCP + (24 + (lo4 >> 1)) * XCP_PITCH + q * 32;
                uint4 da = *(const uint4*)rp;
                uint4 db = *(const uint4*)(rp + 16);
                uint4 bb = { __builtin_amdgcn_perm(da.y, da.x, selp),
                             __builtin_amdgcn_perm(da.w, da.z, selp),
                             __builtin_amdgcn_perm(db.y, db.x, selp),
                             __builtin_amdgcn_perm(db.w, db.z, selp) };
                o3 = __builtin_amdgcn_mfma_f32_16x16x32_f16(pah, u2h8(bb), o3, 0, 0, 0);
            }

            // Rotate pipeline state.
            cc0 = nc0; cc1 = nc1; rcu0 = nru0; rcu1 = nru1;
            R0 = NR0; R1 = NR1;
        }
    }

    // ---- cross-wave combine: wave1 dumps partials into its own XCP region ----
    if (wid == 1) {
        char* ST = XCP;
        *(v4f*)(ST + lane * 68 +  0) = o0;
        *(v4f*)(ST + lane * 68 + 16) = o1;
        *(v4f*)(ST + lane * 68 + 32) = o2;
        *(v4f*)(ST + lane * 68 + 48) = o3;
        *(float*)(ST + 64 * 68 + lane * 4) = lsum;
    }
    __syncthreads();
    if (wid == 1) return;
    {
        const char* ST = lds_raw + WAVE_LDS;
        o0 += *(const v4f*)(ST + lane * 68 +  0);
        o1 += *(const v4f*)(ST + lane * 68 + 16);
        o2 += *(const v4f*)(ST + lane * 68 + 32);
        o3 += *(const v4f*)(ST + lane * 68 + 48);
        lsum += *(const float*)(ST + 64 * 68 + lane * 4);
    }

    lsum += __shfl_xor(lsum, 16, 64);
    lsum += __shfl_xor(lsum, 32, 64);
    float inv = lsum > 0.f ? 1.f / lsum : 0.f;
    float i0 = __shfl(inv, 4*q + 0);
    float i1 = __shfl(inv, 4*q + 1);
    float i2 = __shfl(inv, 4*q + 2);
    float i3 = __shfl(inv, 4*q + 3);

    int m0 = t0 + q * 4;
    if (m0 + 0 < n_nodes) { float* p = out + (size_t)(m0 + 0) * 64 + lo4;
        p[0] = o0[0]*i0; p[16] = o1[0]*i0; p[32] = o2[0]*i0; p[48] = o3[0]*i0; }
    if (m0 + 1 < n_nodes) { float* p = out + (size_t)(m0 + 1) * 64 + lo4;
        p[0] = o0[1]*i1; p[16] = o1[1]*i1; p[32] = o2[1]*i1; p[48] = o3[1]*i1; }
    if (m0 + 2 < n_nodes) { float* p = out + (size_t)(m0 + 2) * 64 + lo4;
        p[0] = o0[2]*i2; p[16] = o1[2]*i2; p[32] = o2[2]*i2; p[48] = o3[2]*i2; }
    if (m0 + 3 < n_nodes) { float* p = out + (size_t)(m0 + 3) * 64 + lo4;
        p[0] = o0[3]*i3; p[16] = o1[3]*i3; p[32] = o2[3]*i3; p[48] = o3[3]*i3; }
}

extern "C" void kernel_launch(void* const* d_in, const int* in_sizes, int n_in,
                              void* d_out, int out_size, void* d_ws, size_t ws_size,
                              hipStream_t stream) {
    const float* x        = (const float*)d_in[0];
    const float* beta     = (const float*)d_in[1];
    const int*   edge_row = (const int*)d_in[2];
    const int*   edge_col = (const int*)d_in[3];
    float* out = (float*)d_out;

    int n_nodes = in_sizes[0] / D_FEAT;
    int n_edges = in_sizes[2];

    char* ws = (char*)d_ws;
    unsigned* rnt = (unsigned*)ws;                           // packed {rn', s}
    size_t off0 = ((size_t)n_nodes * 4 + 255) & ~(size_t)255;
    int* row_ptr = (int*)(ws + off0);
    size_t off1 = off0 + (((size_t)(n_nodes + 1) * 4 + 255) & ~(size_t)255);
    unsigned* xq = (unsigned*)(ws + off1);                   // u8 table, 64 B/node

    {
        int nb_prep = (n_nodes * 16 + 255) / 256;
        int nb_rp   = (n_edges + 255) / 256;
        agnn_prep<<<nb_prep + nb_rp, 256, 0, stream>>>(
            x, rnt, xq, edge_row, row_ptr, n_nodes, n_edges, nb_prep);
    }
    {
        int tiles = (n_nodes + 15) / 16;
        agnn_fused<<<tiles, 128, 0, stream>>>(beta, edge_col, row_ptr,
                                              rnt, (const uint4*)xq, out, n_nodes);
    }
}